// Round 10
// baseline (808.358 us; speedup 1.0000x reference)
//
#include <hip/hip_runtime.h>
#include <hip/hip_fp16.h>

#define EMBED 128
#define CHUNK 8             // gathers per inner batch

// int8 storage: per-row symmetric quant (R4/R7-proven, absmax 4.96e-5).
// q = rint(h*127/amax)+128 in [1,255]; h = (q-128)*s, s = amax/127.
// SpMM: acc = sum q*(v*s_col), cb = sum (v*s_col); h_out = acc - 128*cb.

// ---------------- CSR build step 1: per-row degree count + fused fp32->int8 cvt ------

__global__ __launch_bounds__(256) void count_cvt(const int* __restrict__ row,
                                                 int* __restrict__ deg, int E, int CC,
                                                 const float* __restrict__ uE,
                                                 const float* __restrict__ iE,
                                                 unsigned* __restrict__ h0,
                                                 float* __restrict__ sc0,
                                                 int userNum, int N) {
    const int tid = threadIdx.x;
    if ((int)blockIdx.x >= CC) {
        // ---- cvt branch: feats -> int8 per-row (2 rows/wave, 32 lanes each) ----
        int vb   = (int)blockIdx.x - CC;
        int gid  = vb * 256 + tid;
        int wave = gid >> 6;
        int lane = tid & 63;
        int half = lane >> 5;
        int l32  = lane & 31;
        int r    = wave * 2 + half;
        if (r >= N) return;
        const float* src = (r < userNum) ? (uE + (size_t)r * EMBED)
                                         : (iE + (size_t)(r - userNum) * EMBED);
        float4 a = *(const float4*)(src + 4 * l32);
        float am = fmaxf(fmaxf(fabsf(a.x), fabsf(a.y)), fmaxf(fabsf(a.z), fabsf(a.w)));
        #pragma unroll
        for (int off = 16; off > 0; off >>= 1)
            am = fmaxf(am, __shfl_xor(am, off));
        float s   = am * (1.f / 127.f);
        float inv = (am > 0.f) ? (127.f / am) : 0.f;
        int q0 = (int)rintf(a.x * inv) + 128;
        int q1 = (int)rintf(a.y * inv) + 128;
        int q2 = (int)rintf(a.z * inv) + 128;
        int q3 = (int)rintf(a.w * inv) + 128;
        unsigned w = (unsigned)q0 | ((unsigned)q1 << 8) | ((unsigned)q2 << 16)
                   | ((unsigned)q3 << 24);
        h0[(size_t)r * 32 + l32] = w;
        if (l32 == 0) sc0[r] = s;
        return;
    }
    // ---- count branch: 4 edges/thread, vectorized row read ----
    int base = ((int)blockIdx.x * 256 + tid) * 4;
    if (base + 3 < E) {
        int4 r4 = *(const int4*)(row + base);
        atomicAdd(&deg[r4.x], 1);
        atomicAdd(&deg[r4.y], 1);
        atomicAdd(&deg[r4.z], 1);
        atomicAdd(&deg[r4.w], 1);
    } else {
        for (int j = 0; j < 4; ++j) {
            int idx = base + j;
            if (idx < E) atomicAdd(&deg[row[idx]], 1);
        }
    }
}

// ---------------- CSR build step 2: single-block scan deg -> rs (+cursor init) -------

__global__ __launch_bounds__(1024) void scan_deg(const int* __restrict__ deg,
                                                 int* __restrict__ rs,
                                                 int* __restrict__ cursor,
                                                 int N, int E) {
    __shared__ int part[1024];
    const int tid = threadIdx.x;
    const int per = (N + 1023) / 1024;
    int lo = tid * per;
    int hi = lo + per; if (hi > N) hi = N;
    int sum = 0;
    for (int i = lo; i < hi; ++i) sum += deg[i];
    part[tid] = sum;
    __syncthreads();
    for (int off = 1; off < 1024; off <<= 1) {
        int t = (tid >= off) ? part[tid - off] : 0;
        __syncthreads();
        part[tid] += t;
        __syncthreads();
    }
    int run = part[tid] - sum;   // exclusive base for this thread's range
    for (int i = lo; i < hi; ++i) {
        rs[i] = run;
        cursor[i] = run;
        run += deg[i];
    }
    if (tid == 1023) rs[N] = E;
}

// ---------------- CSR build step 3: scatter edges to row segments --------------------

__global__ __launch_bounds__(256) void scatter_edges(const int* __restrict__ row,
                                                     const int* __restrict__ col,
                                                     const float* __restrict__ val,
                                                     int* __restrict__ cursor,
                                                     int2* __restrict__ edges, int E) {
    int base = ((int)blockIdx.x * 256 + threadIdx.x) * 4;
    if (base + 3 < E) {
        int4   r4 = *(const int4*)(row + base);
        int4   c4 = *(const int4*)(col + base);
        float4 v4 = *(const float4*)(val + base);
        int p0 = atomicAdd(&cursor[r4.x], 1);
        int p1 = atomicAdd(&cursor[r4.y], 1);
        int p2 = atomicAdd(&cursor[r4.z], 1);
        int p3 = atomicAdd(&cursor[r4.w], 1);
        edges[p0] = make_int2(c4.x, __float_as_int(v4.x));
        edges[p1] = make_int2(c4.y, __float_as_int(v4.y));
        edges[p2] = make_int2(c4.z, __float_as_int(v4.z));
        edges[p3] = make_int2(c4.w, __float_as_int(v4.w));
    } else {
        for (int j = 0; j < 4; ++j) {
            int idx = base + j;
            if (idx < E) {
                int p = atomicAdd(&cursor[row[idx]], 1);
                edges[p] = make_int2(col[idx], __float_as_int(val[idx]));
            }
        }
    }
}

// ---------------- gather loop: lane-held edges + shfl distribution, int8 h -----------

#define GATHER_LOOP_I8(HSRC, SCSRC)                                           \
    for (int t = s; t < e; t += 32) {                                         \
        int ecl = t + l32;                                                    \
        ecl = (ecl < e) ? ecl : (e - 1);                                      \
        int2 myed = edges[ecl];                                               \
        float mvs = __int_as_float(myed.y) * SCSRC[myed.x];                   \
        int nb = e - t;                                                       \
        nb = (nb < 32) ? nb : 32;                                             \
        for (int k = 0; k < nb; k += CHUNK) {                                 \
            unsigned raw[CHUNK];                                              \
            float tv[CHUNK];                                                  \
            _Pragma("unroll")                                                 \
            for (int j = 0; j < CHUNK; ++j) {                                 \
                int   c  = __shfl(myed.x, k + j, 32);                         \
                float tj = __shfl(mvs, k + j, 32);                            \
                bool ok  = (k + j) < nb;                                      \
                tv[j]    = ok ? tj : 0.f;                                     \
                raw[j]   = HSRC[(size_t)c * 32 + l32];                        \
            }                                                                 \
            _Pragma("unroll")                                                 \
            for (int j = 0; j < CHUNK; ++j) {                                 \
                unsigned r = raw[j];                                          \
                float tj = tv[j];                                             \
                cb += tj;                                                     \
                acc.x = fmaf((float)(unsigned char)(r),       tj, acc.x);     \
                acc.y = fmaf((float)(unsigned char)(r >> 8),  tj, acc.y);     \
                acc.z = fmaf((float)(unsigned char)(r >> 16), tj, acc.z);     \
                acc.w = fmaf((float)(unsigned char)(r >> 24), tj, acc.w);     \
            }                                                                 \
        }                                                                     \
    }

// ---------------- SpMM: 2 rows/wave (32 lanes each), int8 h, fp32 acc ----------------
// R7-proven: 54.6 us/dispatch, VALUBusy 78%.

__global__ void spmm_kernel(const int* __restrict__ rs, const int2* __restrict__ edges,
                            const unsigned* __restrict__ hin,
                            const float* __restrict__ scin,
                            unsigned* __restrict__ hout, float* __restrict__ scout,
                            int N) {
    int gid  = blockIdx.x * blockDim.x + threadIdx.x;
    int wave = gid >> 6;
    int lane = threadIdx.x & 63;
    int half = lane >> 5;
    int l32  = lane & 31;
    int row  = wave * 2 + half;
    if (row >= N) return;
    int s = rs[row], e = rs[row + 1];
    float4 acc = make_float4(0.f, 0.f, 0.f, 0.f);
    float cb = 0.f;

    GATHER_LOOP_I8(hin, scin)

    float b = 128.f * cb;
    acc.x -= b; acc.y -= b; acc.z -= b; acc.w -= b;
    float am = fmaxf(fmaxf(fabsf(acc.x), fabsf(acc.y)), fmaxf(fabsf(acc.z), fabsf(acc.w)));
    #pragma unroll
    for (int off = 16; off > 0; off >>= 1)
        am = fmaxf(am, __shfl_xor(am, off));
    float sq  = am * (1.f / 127.f);
    float inv = (am > 0.f) ? (127.f / am) : 0.f;
    int q0 = (int)rintf(acc.x * inv) + 128;
    int q1 = (int)rintf(acc.y * inv) + 128;
    int q2 = (int)rintf(acc.z * inv) + 128;
    int q3 = (int)rintf(acc.w * inv) + 128;
    unsigned w = (unsigned)q0 | ((unsigned)q1 << 8) | ((unsigned)q2 << 16)
               | ((unsigned)q3 << 24);
    hout[(size_t)row * 32 + l32] = w;
    if (l32 == 0) scout[row] = sq;
}

// ---------------- fused tail: per pair b, half0 = u-row, half1 = v-row ----------------

__global__ void spmm_pair(const int* __restrict__ rs, const int2* __restrict__ edges,
                          const unsigned* __restrict__ h1, const float* __restrict__ sc1,
                          const unsigned* __restrict__ h2, const float* __restrict__ sc2,
                          const float* __restrict__ uE, const float* __restrict__ iE,
                          const int* __restrict__ uIdx, const int* __restrict__ vIdx,
                          float* __restrict__ out, int B, int userNum) {
    int gid  = blockIdx.x * blockDim.x + threadIdx.x;
    int wave = gid >> 6;
    int lane = threadIdx.x & 63;
    int half = lane >> 5;
    int l32  = lane & 31;
    if (wave >= B) return;
    int row;
    const float* emb;
    if (half == 0) {
        int u = uIdx[wave];
        row = u;
        emb = uE + (size_t)u * EMBED;
    } else {
        int it = vIdx[wave];
        row = userNum + it;
        emb = iE + (size_t)it * EMBED;
    }
    float4 acc = *(const float4*)(emb + 4 * l32);   // feats, exact fp32
    {
        unsigned r1 = h1[(size_t)row * 32 + l32];
        unsigned r2 = h2[(size_t)row * 32 + l32];
        float s1 = sc1[row];
        float s2 = sc2[row];
        acc.x += ((float)(unsigned char)(r1)       - 128.f) * s1
               + ((float)(unsigned char)(r2)       - 128.f) * s2;
        acc.y += ((float)(unsigned char)(r1 >> 8)  - 128.f) * s1
               + ((float)(unsigned char)(r2 >> 8)  - 128.f) * s2;
        acc.z += ((float)(unsigned char)(r1 >> 16) - 128.f) * s1
               + ((float)(unsigned char)(r2 >> 16) - 128.f) * s2;
        acc.w += ((float)(unsigned char)(r1 >> 24) - 128.f) * s1
               + ((float)(unsigned char)(r2 >> 24) - 128.f) * s2;
    }
    float cb = 0.f;
    int s = rs[row], e = rs[row + 1];

    GATHER_LOOP_I8(h2, sc2)

    float b = 128.f * cb;
    acc.x -= b; acc.y -= b; acc.z -= b; acc.w -= b;

    float ox = __shfl_xor(acc.x, 32);
    float oy = __shfl_xor(acc.y, 32);
    float oz = __shfl_xor(acc.z, 32);
    float ow = __shfl_xor(acc.w, 32);
    float sdot = acc.x * ox + acc.y * oy + acc.z * oz + acc.w * ow;
    #pragma unroll
    for (int off = 16; off > 0; off >>= 1) sdot += __shfl_down(sdot, off, 32);
    sdot += __shfl_down(sdot, 32);
    if (lane == 0) out[wave] = sdot * (1.f / 32.f);
}

// ---------------- launch ----------------

extern "C" void kernel_launch(void* const* d_in, const int* in_sizes, int n_in,
                              void* d_out, int out_size, void* d_ws, size_t ws_size,
                              hipStream_t stream) {
    const float* uE      = (const float*)d_in[0];
    const float* iE      = (const float*)d_in[1];
    const float* L_val   = (const float*)d_in[2];
    const int*   L_row   = (const int*)d_in[3];
    const int*   L_col   = (const int*)d_in[4];
    const int*   userIdx = (const int*)d_in[5];
    const int*   itemIdx = (const int*)d_in[6];

    const int userNum = in_sizes[0] / EMBED;   // 100000
    const int itemNum = in_sizes[1] / EMBED;   // 50000
    const int N = userNum + itemNum;           // 150000
    const int E = in_sizes[2];                 // 2000000
    const int B = in_sizes[5];                 // 16384
    float* out = (float*)d_out;

    char* ws = (char*)d_ws;
    size_t off = 0;
    auto alloc = [&](size_t bytes) -> void* {
        void* p = ws + off;
        off += (bytes + 1023) & ~(size_t)1023;
        return p;
    };
    unsigned* h0 = (unsigned*)alloc((size_t)N * EMBED);   // int8
    unsigned* h1 = (unsigned*)alloc((size_t)N * EMBED);   // int8
    unsigned* h2 = (unsigned*)alloc((size_t)N * EMBED);   // int8
    float* sc0   = (float*)alloc((size_t)N * 4);
    float* sc1   = (float*)alloc((size_t)N * 4);
    float* sc2   = (float*)alloc((size_t)N * 4);
    int2*  edges = (int2*) alloc((size_t)E * 8 + 256);    // +slack
    int*   rs    = (int*)  alloc((size_t)(N + 1) * 4);
    int*   deg   = (int*)  alloc((size_t)(N + 1) * 4);
    int*   cursor= (int*)  alloc((size_t)(N + 1) * 4);
    (void)off; (void)ws_size; (void)n_in; (void)out_size;

    // zero deg
    (void)hipMemsetAsync(deg, 0, (size_t)N * 4, stream);

    // CSR build: count (+fused cvt) -> scan -> scatter
    const int CC  = (E + 1023) / 1024;     // 4 edges/thread, 256 threads
    const int CVB = (N + 7) / 8;
    count_cvt<<<CC + CVB, 256, 0, stream>>>(L_row, deg, E, CC,
                                            uE, iE, h0, sc0, userNum, N);
    scan_deg<<<1, 1024, 0, stream>>>(deg, rs, cursor, N, E);
    scatter_edges<<<CC, 256, 0, stream>>>(L_row, L_col, L_val, cursor, edges, E);

    // propagation: 8 rows per 256-thread block (2 rows/wave)
    const int spmm_blocks = (N + 7) / 8;
    spmm_kernel<<<spmm_blocks, 256, 0, stream>>>(rs, edges, h0, sc0, h1, sc1, N);
    spmm_kernel<<<spmm_blocks, 256, 0, stream>>>(rs, edges, h1, sc1, h2, sc2, N);

    // fused layer-3-restricted spmm + layer-sum + dot
    spmm_pair<<<(B + 3) / 4, 256, 0, stream>>>(rs, edges, h1, sc1, h2, sc2, uE, iE,
                                               userIdx, itemIdx, out, B, userNum);
}

// Round 11
// 493.082 us; speedup vs baseline: 1.6394x; 1.6394x over previous
//
#include <hip/hip_runtime.h>
#include <hip/hip_fp16.h>

#define EMBED 128
#define CHUNK 8             // gathers per inner batch

// int8 storage: per-row symmetric quant (R4/R7-proven, absmax 4.96e-5).
// q = rint(h*127/amax)+128 in [1,255]; h = (q-128)*s, s = amax/127.
// SpMM: acc = sum q*(v*s_col), cb = sum (v*s_col); h_out = acc - 128*cb.

// ---------------- CSR build step 1: per-row degree count + fused fp32->int8 cvt ------

__global__ __launch_bounds__(256) void count_cvt(const int* __restrict__ row,
                                                 int* __restrict__ deg, int E, int CC,
                                                 const float* __restrict__ uE,
                                                 const float* __restrict__ iE,
                                                 unsigned* __restrict__ h0,
                                                 float* __restrict__ sc0,
                                                 int userNum, int N) {
    const int tid = threadIdx.x;
    if ((int)blockIdx.x >= CC) {
        // ---- cvt branch: feats -> int8 per-row (2 rows/wave, 32 lanes each) ----
        int vb   = (int)blockIdx.x - CC;
        int gid  = vb * 256 + tid;
        int wave = gid >> 6;
        int lane = tid & 63;
        int half = lane >> 5;
        int l32  = lane & 31;
        int r    = wave * 2 + half;
        if (r >= N) return;
        const float* src = (r < userNum) ? (uE + (size_t)r * EMBED)
                                         : (iE + (size_t)(r - userNum) * EMBED);
        float4 a = *(const float4*)(src + 4 * l32);
        float am = fmaxf(fmaxf(fabsf(a.x), fabsf(a.y)), fmaxf(fabsf(a.z), fabsf(a.w)));
        #pragma unroll
        for (int off = 16; off > 0; off >>= 1)
            am = fmaxf(am, __shfl_xor(am, off));
        float s   = am * (1.f / 127.f);
        float inv = (am > 0.f) ? (127.f / am) : 0.f;
        int q0 = (int)rintf(a.x * inv) + 128;
        int q1 = (int)rintf(a.y * inv) + 128;
        int q2 = (int)rintf(a.z * inv) + 128;
        int q3 = (int)rintf(a.w * inv) + 128;
        unsigned w = (unsigned)q0 | ((unsigned)q1 << 8) | ((unsigned)q2 << 16)
                   | ((unsigned)q3 << 24);
        h0[(size_t)r * 32 + l32] = w;
        if (l32 == 0) sc0[r] = s;
        return;
    }
    // ---- count branch: 4 edges/thread, vectorized row read ----
    int base = ((int)blockIdx.x * 256 + tid) * 4;
    if (base + 3 < E) {
        int4 r4 = *(const int4*)(row + base);
        atomicAdd(&deg[r4.x], 1);
        atomicAdd(&deg[r4.y], 1);
        atomicAdd(&deg[r4.z], 1);
        atomicAdd(&deg[r4.w], 1);
    } else {
        for (int j = 0; j < 4; ++j) {
            int idx = base + j;
            if (idx < E) atomicAdd(&deg[row[idx]], 1);
        }
    }
}

// ---------------- CSR build step 2: hierarchical scan (full-grid, coalesced) ---------
// R10 lesson: single-block serial scan = 336 us (1 CU, uncoalesced latency chain).

__global__ __launch_bounds__(1024) void scanA(const int* __restrict__ deg,
                                              int* __restrict__ rsl,
                                              int* __restrict__ bsum, int N) {
    __shared__ int sh[1024];
    const int tid = threadIdx.x;
    int i = (int)blockIdx.x * 1024 + tid;
    int x = (i < N) ? deg[i] : 0;
    sh[tid] = x;
    __syncthreads();
    for (int off = 1; off < 1024; off <<= 1) {
        int t = (tid >= off) ? sh[tid - off] : 0;
        __syncthreads();
        sh[tid] += t;
        __syncthreads();
    }
    if (i < N) rsl[i] = sh[tid] - x;          // block-local exclusive
    if (tid == 1023) bsum[blockIdx.x] = sh[1023];
}

__global__ __launch_bounds__(256) void scanB(int* __restrict__ bsum, int nb) {
    __shared__ int sh[256];
    const int tid = threadIdx.x;
    int x = (tid < nb) ? bsum[tid] : 0;
    sh[tid] = x;
    __syncthreads();
    for (int off = 1; off < 256; off <<= 1) {
        int t = (tid >= off) ? sh[tid - off] : 0;
        __syncthreads();
        sh[tid] += t;
        __syncthreads();
    }
    if (tid < nb) bsum[tid] = sh[tid] - x;    // exclusive block offsets
}

__global__ __launch_bounds__(1024) void scanC(const int* __restrict__ rsl,
                                              const int* __restrict__ bsum,
                                              int* __restrict__ rs,
                                              int* __restrict__ cursor, int N, int E) {
    int i = (int)blockIdx.x * 1024 + threadIdx.x;
    if (i < N) {
        int v = rsl[i] + bsum[blockIdx.x];
        rs[i] = v;
        cursor[i] = v;
    }
    if (i == 0) rs[N] = E;
}

// ---------------- CSR build step 3: scatter edges to row segments --------------------

__global__ __launch_bounds__(256) void scatter_edges(const int* __restrict__ row,
                                                     const int* __restrict__ col,
                                                     const float* __restrict__ val,
                                                     int* __restrict__ cursor,
                                                     int2* __restrict__ edges, int E) {
    int base = ((int)blockIdx.x * 256 + threadIdx.x) * 4;
    if (base + 3 < E) {
        int4   r4 = *(const int4*)(row + base);
        int4   c4 = *(const int4*)(col + base);
        float4 v4 = *(const float4*)(val + base);
        int p0 = atomicAdd(&cursor[r4.x], 1);
        int p1 = atomicAdd(&cursor[r4.y], 1);
        int p2 = atomicAdd(&cursor[r4.z], 1);
        int p3 = atomicAdd(&cursor[r4.w], 1);
        edges[p0] = make_int2(c4.x, __float_as_int(v4.x));
        edges[p1] = make_int2(c4.y, __float_as_int(v4.y));
        edges[p2] = make_int2(c4.z, __float_as_int(v4.z));
        edges[p3] = make_int2(c4.w, __float_as_int(v4.w));
    } else {
        for (int j = 0; j < 4; ++j) {
            int idx = base + j;
            if (idx < E) {
                int p = atomicAdd(&cursor[row[idx]], 1);
                edges[p] = make_int2(col[idx], __float_as_int(val[idx]));
            }
        }
    }
}

// ---------------- gather loop: lane-held edges + shfl distribution, int8 h -----------

#define GATHER_LOOP_I8(HSRC, SCSRC)                                           \
    for (int t = s; t < e; t += 32) {                                         \
        int ecl = t + l32;                                                    \
        ecl = (ecl < e) ? ecl : (e - 1);                                      \
        int2 myed = edges[ecl];                                               \
        float mvs = __int_as_float(myed.y) * SCSRC[myed.x];                   \
        int nb = e - t;                                                       \
        nb = (nb < 32) ? nb : 32;                                             \
        for (int k = 0; k < nb; k += CHUNK) {                                 \
            unsigned raw[CHUNK];                                              \
            float tv[CHUNK];                                                  \
            _Pragma("unroll")                                                 \
            for (int j = 0; j < CHUNK; ++j) {                                 \
                int   c  = __shfl(myed.x, k + j, 32);                         \
                float tj = __shfl(mvs, k + j, 32);                            \
                bool ok  = (k + j) < nb;                                      \
                tv[j]    = ok ? tj : 0.f;                                     \
                raw[j]   = HSRC[(size_t)c * 32 + l32];                        \
            }                                                                 \
            _Pragma("unroll")                                                 \
            for (int j = 0; j < CHUNK; ++j) {                                 \
                unsigned r = raw[j];                                          \
                float tj = tv[j];                                             \
                cb += tj;                                                     \
                acc.x = fmaf((float)(unsigned char)(r),       tj, acc.x);     \
                acc.y = fmaf((float)(unsigned char)(r >> 8),  tj, acc.y);     \
                acc.z = fmaf((float)(unsigned char)(r >> 16), tj, acc.z);     \
                acc.w = fmaf((float)(unsigned char)(r >> 24), tj, acc.w);     \
            }                                                                 \
        }                                                                     \
    }

// ---------------- SpMM: 2 rows/wave (32 lanes each), int8 h, fp32 acc ----------------
// R7-proven: 54.6 us/dispatch, VALUBusy 78%.

__global__ void spmm_kernel(const int* __restrict__ rs, const int2* __restrict__ edges,
                            const unsigned* __restrict__ hin,
                            const float* __restrict__ scin,
                            unsigned* __restrict__ hout, float* __restrict__ scout,
                            int N) {
    int gid  = blockIdx.x * blockDim.x + threadIdx.x;
    int wave = gid >> 6;
    int lane = threadIdx.x & 63;
    int half = lane >> 5;
    int l32  = lane & 31;
    int row  = wave * 2 + half;
    if (row >= N) return;
    int s = rs[row], e = rs[row + 1];
    float4 acc = make_float4(0.f, 0.f, 0.f, 0.f);
    float cb = 0.f;

    GATHER_LOOP_I8(hin, scin)

    float b = 128.f * cb;
    acc.x -= b; acc.y -= b; acc.z -= b; acc.w -= b;
    float am = fmaxf(fmaxf(fabsf(acc.x), fabsf(acc.y)), fmaxf(fabsf(acc.z), fabsf(acc.w)));
    #pragma unroll
    for (int off = 16; off > 0; off >>= 1)
        am = fmaxf(am, __shfl_xor(am, off));
    float sq  = am * (1.f / 127.f);
    float inv = (am > 0.f) ? (127.f / am) : 0.f;
    int q0 = (int)rintf(acc.x * inv) + 128;
    int q1 = (int)rintf(acc.y * inv) + 128;
    int q2 = (int)rintf(acc.z * inv) + 128;
    int q3 = (int)rintf(acc.w * inv) + 128;
    unsigned w = (unsigned)q0 | ((unsigned)q1 << 8) | ((unsigned)q2 << 16)
               | ((unsigned)q3 << 24);
    hout[(size_t)row * 32 + l32] = w;
    if (l32 == 0) scout[row] = sq;
}

// ---------------- fused tail: per pair b, half0 = u-row, half1 = v-row ----------------

__global__ void spmm_pair(const int* __restrict__ rs, const int2* __restrict__ edges,
                          const unsigned* __restrict__ h1, const float* __restrict__ sc1,
                          const unsigned* __restrict__ h2, const float* __restrict__ sc2,
                          const float* __restrict__ uE, const float* __restrict__ iE,
                          const int* __restrict__ uIdx, const int* __restrict__ vIdx,
                          float* __restrict__ out, int B, int userNum) {
    int gid  = blockIdx.x * blockDim.x + threadIdx.x;
    int wave = gid >> 6;
    int lane = threadIdx.x & 63;
    int half = lane >> 5;
    int l32  = lane & 31;
    if (wave >= B) return;
    int row;
    const float* emb;
    if (half == 0) {
        int u = uIdx[wave];
        row = u;
        emb = uE + (size_t)u * EMBED;
    } else {
        int it = vIdx[wave];
        row = userNum + it;
        emb = iE + (size_t)it * EMBED;
    }
    float4 acc = *(const float4*)(emb + 4 * l32);   // feats, exact fp32
    {
        unsigned r1 = h1[(size_t)row * 32 + l32];
        unsigned r2 = h2[(size_t)row * 32 + l32];
        float s1 = sc1[row];
        float s2 = sc2[row];
        acc.x += ((float)(unsigned char)(r1)       - 128.f) * s1
               + ((float)(unsigned char)(r2)       - 128.f) * s2;
        acc.y += ((float)(unsigned char)(r1 >> 8)  - 128.f) * s1
               + ((float)(unsigned char)(r2 >> 8)  - 128.f) * s2;
        acc.z += ((float)(unsigned char)(r1 >> 16) - 128.f) * s1
               + ((float)(unsigned char)(r2 >> 16) - 128.f) * s2;
        acc.w += ((float)(unsigned char)(r1 >> 24) - 128.f) * s1
               + ((float)(unsigned char)(r2 >> 24) - 128.f) * s2;
    }
    float cb = 0.f;
    int s = rs[row], e = rs[row + 1];

    GATHER_LOOP_I8(h2, sc2)

    float b = 128.f * cb;
    acc.x -= b; acc.y -= b; acc.z -= b; acc.w -= b;

    float ox = __shfl_xor(acc.x, 32);
    float oy = __shfl_xor(acc.y, 32);
    float oz = __shfl_xor(acc.z, 32);
    float ow = __shfl_xor(acc.w, 32);
    float sdot = acc.x * ox + acc.y * oy + acc.z * oz + acc.w * ow;
    #pragma unroll
    for (int off = 16; off > 0; off >>= 1) sdot += __shfl_down(sdot, off, 32);
    sdot += __shfl_down(sdot, 32);
    if (lane == 0) out[wave] = sdot * (1.f / 32.f);
}

// ---------------- launch ----------------

extern "C" void kernel_launch(void* const* d_in, const int* in_sizes, int n_in,
                              void* d_out, int out_size, void* d_ws, size_t ws_size,
                              hipStream_t stream) {
    const float* uE      = (const float*)d_in[0];
    const float* iE      = (const float*)d_in[1];
    const float* L_val   = (const float*)d_in[2];
    const int*   L_row   = (const int*)d_in[3];
    const int*   L_col   = (const int*)d_in[4];
    const int*   userIdx = (const int*)d_in[5];
    const int*   itemIdx = (const int*)d_in[6];

    const int userNum = in_sizes[0] / EMBED;   // 100000
    const int itemNum = in_sizes[1] / EMBED;   // 50000
    const int N = userNum + itemNum;           // 150000
    const int E = in_sizes[2];                 // 2000000
    const int B = in_sizes[5];                 // 16384
    float* out = (float*)d_out;

    char* ws = (char*)d_ws;
    size_t off = 0;
    auto alloc = [&](size_t bytes) -> void* {
        void* p = ws + off;
        off += (bytes + 1023) & ~(size_t)1023;
        return p;
    };
    unsigned* h0 = (unsigned*)alloc((size_t)N * EMBED);   // int8
    unsigned* h1 = (unsigned*)alloc((size_t)N * EMBED);   // int8
    unsigned* h2 = (unsigned*)alloc((size_t)N * EMBED);   // int8
    float* sc0   = (float*)alloc((size_t)N * 4);
    float* sc1   = (float*)alloc((size_t)N * 4);
    float* sc2   = (float*)alloc((size_t)N * 4);
    int2*  edges = (int2*) alloc((size_t)E * 8 + 256);    // +slack
    int*   rs    = (int*)  alloc((size_t)(N + 1) * 4);
    int*   rsl   = (int*)  alloc((size_t)(N + 1) * 4);
    int*   deg   = (int*)  alloc((size_t)(N + 1) * 4);
    int*   cursor= (int*)  alloc((size_t)(N + 1) * 4);
    int*   bsum  = (int*)  alloc(1024);
    (void)off; (void)ws_size; (void)n_in; (void)out_size;

    // zero deg
    (void)hipMemsetAsync(deg, 0, (size_t)N * 4, stream);

    // CSR build: count (+fused cvt) -> hierarchical scan -> scatter
    const int CC  = (E + 1023) / 1024;          // 4 edges/thread, 256 threads
    const int CVB = (N + 7) / 8;
    const int SB  = (N + 1023) / 1024;          // 147 scan blocks
    count_cvt<<<CC + CVB, 256, 0, stream>>>(L_row, deg, E, CC,
                                            uE, iE, h0, sc0, userNum, N);
    scanA<<<SB, 1024, 0, stream>>>(deg, rsl, bsum, N);
    scanB<<<1, 256, 0, stream>>>(bsum, SB);
    scanC<<<SB, 1024, 0, stream>>>(rsl, bsum, rs, cursor, N, E);
    scatter_edges<<<CC, 256, 0, stream>>>(L_row, L_col, L_val, cursor, edges, E);

    // propagation: 8 rows per 256-thread block (2 rows/wave)
    const int spmm_blocks = (N + 7) / 8;
    spmm_kernel<<<spmm_blocks, 256, 0, stream>>>(rs, edges, h0, sc0, h1, sc1, N);
    spmm_kernel<<<spmm_blocks, 256, 0, stream>>>(rs, edges, h1, sc1, h2, sc2, N);

    // fused layer-3-restricted spmm + layer-sum + dot
    spmm_pair<<<(B + 3) / 4, 256, 0, stream>>>(rs, edges, h1, sc1, h2, sc2, uE, iE,
                                               userIdx, itemIdx, out, B, userNum);
}

// Round 13
// 317.283 us; speedup vs baseline: 2.5478x; 1.5541x over previous
//
#include <hip/hip_runtime.h>
#include <hip/hip_fp16.h>

#define EMBED 128
#define CHUNK 8             // gathers per inner batch
#define T_TILE 4096
#define NB_SH 10            // 1024 rows per bucket
#define BCAP 32768          // fixed per-bucket capacity (avg ~13.6K)

// int8 storage: per-row symmetric quant (R4/R7-proven, absmax 4.96e-5).
// q = rint(h*127/amax)+128 in [1,255]; h = (q-128)*s, s = amax/127.
// SpMM: acc = sum q*(v*s_col), cb = sum (v*s_col); h_out = acc - 128*cb.
//
// CSR build = bucket sort (R2-R9 proven): LDS-staged contiguous writes avoid the
// 8x write amplification that killed the direct scatter (R11: 129 MB written,
// 163 us). cvt fused into passA grid (R8-proven).

// ---------------- CSR build: passA (bucket sort) + fused fp32->int8 cvt --------------

__global__ __launch_bounds__(256) void passA_cvt(const int* __restrict__ row,
                                                 const int* __restrict__ col,
                                                 const float* __restrict__ val,
                                                 int* __restrict__ bcnt,
                                                 long long* __restrict__ bedges, int E,
                                                 const float* __restrict__ uE,
                                                 const float* __restrict__ iE,
                                                 unsigned* __restrict__ h0,
                                                 float* __restrict__ sc0,
                                                 int userNum, int N, int CA) {
    __shared__ int sh_scan[256];
    __shared__ int sh_start[256];
    __shared__ int sh_cur[256];
    __shared__ int sh_base[256];   // global (fixed-region) base per bucket
    __shared__ long long sh_data[T_TILE];
    __shared__ int sh_gpos[T_TILE];
    const int tid = threadIdx.x;

    if ((int)blockIdx.x >= CA) {
        // ---- cvt branch: feats -> int8 per-row (2 rows/wave, 32 lanes each) ----
        int vb   = (int)blockIdx.x - CA;
        int gid  = vb * 256 + tid;
        int wave = gid >> 6;
        int lane = tid & 63;
        int half = lane >> 5;
        int l32  = lane & 31;
        int r    = wave * 2 + half;
        if (r >= N) return;
        const float* src = (r < userNum) ? (uE + (size_t)r * EMBED)
                                         : (iE + (size_t)(r - userNum) * EMBED);
        float4 a = *(const float4*)(src + 4 * l32);
        float am = fmaxf(fmaxf(fabsf(a.x), fabsf(a.y)), fmaxf(fabsf(a.z), fabsf(a.w)));
        #pragma unroll
        for (int off = 16; off > 0; off >>= 1)
            am = fmaxf(am, __shfl_xor(am, off));
        float s   = am * (1.f / 127.f);
        float inv = (am > 0.f) ? (127.f / am) : 0.f;
        int q0 = (int)rintf(a.x * inv) + 128;
        int q1 = (int)rintf(a.y * inv) + 128;
        int q2 = (int)rintf(a.z * inv) + 128;
        int q3 = (int)rintf(a.w * inv) + 128;
        unsigned w = (unsigned)q0 | ((unsigned)q1 << 8) | ((unsigned)q2 << 16)
                   | ((unsigned)q3 << 24);
        h0[(size_t)r * 32 + l32] = w;
        if (l32 == 0) sc0[r] = s;
        return;
    }

    // ---- passA branch (R2-proven body) ----
    const int t0 = blockIdx.x * T_TILE;

    sh_scan[tid] = 0;
    __syncthreads();
    #pragma unroll
    for (int i = 0; i < T_TILE / 256; ++i) {
        int idx = t0 + i * 256 + tid;
        if (idx < E) atomicAdd(&sh_scan[row[idx] >> NB_SH], 1);
    }
    __syncthreads();
    int x = sh_scan[tid];
    __syncthreads();
    for (int off = 1; off < 256; off <<= 1) {
        int t = (tid >= off) ? sh_scan[tid - off] : 0;
        __syncthreads();
        sh_scan[tid] += t;
        __syncthreads();
    }
    int excl = sh_scan[tid] - x;
    sh_start[tid] = excl;
    sh_cur[tid]   = excl;
    sh_base[tid]  = (x > 0) ? (tid * BCAP + atomicAdd(&bcnt[tid], x)) : 0;
    __syncthreads();
    #pragma unroll
    for (int i = 0; i < T_TILE / 256; ++i) {
        int idx = t0 + i * 256 + tid;
        if (idx < E) {
            int   r = row[idx];
            int   c = col[idx];
            float v = val[idx];
            int   b = r >> NB_SH;
            int   p = atomicAdd(&sh_cur[b], 1);
            unsigned lo = (unsigned)(((r & ((1 << NB_SH) - 1)) << 18) | c);
            sh_data[p] = ((long long)__float_as_int(v) << 32) | (long long)lo;
            sh_gpos[p] = sh_base[b] + (p - sh_start[b]);
        }
    }
    __syncthreads();
    int tot = sh_scan[255];
    for (int p = tid; p < tot; p += 256) {
        bedges[sh_gpos[p]] = sh_data[p];
    }
}

// ---------------- passB: per-bucket row hist + scan -> rs + exact placement ----------

__global__ __launch_bounds__(1024) void passB(const long long* __restrict__ bedges,
                                              const int* __restrict__ bcnt,
                                              int* __restrict__ rs,
                                              int2* __restrict__ edges,
                                              int N, int E, int nbuckets) {
    __shared__ int sh_hist[1024];   // row hist, then reused as cursor
    __shared__ int sh_scan[1024];
    __shared__ int sh_bc[256];
    __shared__ int sh_gbase;
    const int b    = blockIdx.x;
    const int tid  = threadIdx.x;
    const int base = b << NB_SH;
    const int cnt  = bcnt[b];
    const long long* seg = bedges + (size_t)b * BCAP;

    sh_hist[tid] = 0;
    if (tid < nbuckets) sh_bc[tid] = bcnt[tid];
    __syncthreads();
    if (tid == 0) {
        int g = 0;
        for (int j = 0; j < b; ++j) g += sh_bc[j];
        sh_gbase = g;
    }
    for (int k = tid; k < cnt; k += 1024) {
        unsigned lo = (unsigned)seg[k];
        atomicAdd(&sh_hist[lo >> 18], 1);
    }
    __syncthreads();
    int x = sh_hist[tid];
    sh_scan[tid] = x;
    __syncthreads();
    for (int off = 1; off < 1024; off <<= 1) {
        int t = (tid >= off) ? sh_scan[tid - off] : 0;
        __syncthreads();
        sh_scan[tid] += t;
        __syncthreads();
    }
    int excl = sh_scan[tid] - x;
    int gbase = sh_gbase;
    int rrow = base + tid;
    if (rrow < N) rs[rrow] = gbase + excl;
    if (b == nbuckets - 1 && tid == 0) rs[N] = E;
    sh_hist[tid] = excl;
    __syncthreads();
    for (int k = tid; k < cnt; k += 1024) {
        long long be = seg[k];
        unsigned lo = (unsigned)be;
        int p = atomicAdd(&sh_hist[lo >> 18], 1);
        edges[gbase + p] = make_int2((int)(lo & 0x3FFFF), (int)(be >> 32));
    }
}

// ---------------- gather loop: lane-held edges + shfl distribution, int8 h -----------

#define GATHER_LOOP_I8(HSRC, SCSRC)                                           \
    for (int t = s; t < e; t += 32) {                                         \
        int ecl = t + l32;                                                    \
        ecl = (ecl < e) ? ecl : (e - 1);                                      \
        int2 myed = edges[ecl];                                               \
        float mvs = __int_as_float(myed.y) * SCSRC[myed.x];                   \
        int nb = e - t;                                                       \
        nb = (nb < 32) ? nb : 32;                                             \
        for (int k = 0; k < nb; k += CHUNK) {                                 \
            unsigned raw[CHUNK];                                              \
            float tv[CHUNK];                                                  \
            _Pragma("unroll")                                                 \
            for (int j = 0; j < CHUNK; ++j) {                                 \
                int   c  = __shfl(myed.x, k + j, 32);                         \
                float tj = __shfl(mvs, k + j, 32);                            \
                bool ok  = (k + j) < nb;                                      \
                tv[j]    = ok ? tj : 0.f;                                     \
                raw[j]   = HSRC[(size_t)c * 32 + l32];                        \
            }                                                                 \
            _Pragma("unroll")                                                 \
            for (int j = 0; j < CHUNK; ++j) {                                 \
                unsigned r = raw[j];                                          \
                float tj = tv[j];                                             \
                cb += tj;                                                     \
                acc.x = fmaf((float)(unsigned char)(r),       tj, acc.x);     \
                acc.y = fmaf((float)(unsigned char)(r >> 8),  tj, acc.y);     \
                acc.z = fmaf((float)(unsigned char)(r >> 16), tj, acc.z);     \
                acc.w = fmaf((float)(unsigned char)(r >> 24), tj, acc.w);     \
            }                                                                 \
        }                                                                     \
    }

// ---------------- SpMM: 2 rows/wave (32 lanes each), int8 h, fp32 acc ----------------
// R7-proven: 54.6 us/dispatch, VALUBusy 78%.

__global__ void spmm_kernel(const int* __restrict__ rs, const int2* __restrict__ edges,
                            const unsigned* __restrict__ hin,
                            const float* __restrict__ scin,
                            unsigned* __restrict__ hout, float* __restrict__ scout,
                            int N) {
    int gid  = blockIdx.x * blockDim.x + threadIdx.x;
    int wave = gid >> 6;
    int lane = threadIdx.x & 63;
    int half = lane >> 5;
    int l32  = lane & 31;
    int row  = wave * 2 + half;
    if (row >= N) return;
    int s = rs[row], e = rs[row + 1];
    float4 acc = make_float4(0.f, 0.f, 0.f, 0.f);
    float cb = 0.f;

    GATHER_LOOP_I8(hin, scin)

    float b = 128.f * cb;
    acc.x -= b; acc.y -= b; acc.z -= b; acc.w -= b;
    float am = fmaxf(fmaxf(fabsf(acc.x), fabsf(acc.y)), fmaxf(fabsf(acc.z), fabsf(acc.w)));
    #pragma unroll
    for (int off = 16; off > 0; off >>= 1)
        am = fmaxf(am, __shfl_xor(am, off));
    float sq  = am * (1.f / 127.f);
    float inv = (am > 0.f) ? (127.f / am) : 0.f;
    int q0 = (int)rintf(acc.x * inv) + 128;
    int q1 = (int)rintf(acc.y * inv) + 128;
    int q2 = (int)rintf(acc.z * inv) + 128;
    int q3 = (int)rintf(acc.w * inv) + 128;
    unsigned w = (unsigned)q0 | ((unsigned)q1 << 8) | ((unsigned)q2 << 16)
               | ((unsigned)q3 << 24);
    hout[(size_t)row * 32 + l32] = w;
    if (l32 == 0) scout[row] = sq;
}

// ---------------- fused tail: per pair b, half0 = u-row, half1 = v-row ----------------

__global__ void spmm_pair(const int* __restrict__ rs, const int2* __restrict__ edges,
                          const unsigned* __restrict__ h1, const float* __restrict__ sc1,
                          const unsigned* __restrict__ h2, const float* __restrict__ sc2,
                          const float* __restrict__ uE, const float* __restrict__ iE,
                          const int* __restrict__ uIdx, const int* __restrict__ vIdx,
                          float* __restrict__ out, int B, int userNum) {
    int gid  = blockIdx.x * blockDim.x + threadIdx.x;
    int wave = gid >> 6;
    int lane = threadIdx.x & 63;
    int half = lane >> 5;
    int l32  = lane & 31;
    if (wave >= B) return;
    int row;
    const float* emb;
    if (half == 0) {
        int u = uIdx[wave];
        row = u;
        emb = uE + (size_t)u * EMBED;
    } else {
        int it = vIdx[wave];
        row = userNum + it;
        emb = iE + (size_t)it * EMBED;
    }
    float4 acc = *(const float4*)(emb + 4 * l32);   // feats, exact fp32
    {
        unsigned r1 = h1[(size_t)row * 32 + l32];
        unsigned r2 = h2[(size_t)row * 32 + l32];
        float s1 = sc1[row];
        float s2 = sc2[row];
        acc.x += ((float)(unsigned char)(r1)       - 128.f) * s1
               + ((float)(unsigned char)(r2)       - 128.f) * s2;
        acc.y += ((float)(unsigned char)(r1 >> 8)  - 128.f) * s1
               + ((float)(unsigned char)(r2 >> 8)  - 128.f) * s2;
        acc.z += ((float)(unsigned char)(r1 >> 16) - 128.f) * s1
               + ((float)(unsigned char)(r2 >> 16) - 128.f) * s2;
        acc.w += ((float)(unsigned char)(r1 >> 24) - 128.f) * s1
               + ((float)(unsigned char)(r2 >> 24) - 128.f) * s2;
    }
    float cb = 0.f;
    int s = rs[row], e = rs[row + 1];

    GATHER_LOOP_I8(h2, sc2)

    float b = 128.f * cb;
    acc.x -= b; acc.y -= b; acc.z -= b; acc.w -= b;

    float ox = __shfl_xor(acc.x, 32);
    float oy = __shfl_xor(acc.y, 32);
    float oz = __shfl_xor(acc.z, 32);
    float ow = __shfl_xor(acc.w, 32);
    float sdot = acc.x * ox + acc.y * oy + acc.z * oz + acc.w * ow;
    #pragma unroll
    for (int off = 16; off > 0; off >>= 1) sdot += __shfl_down(sdot, off, 32);
    sdot += __shfl_down(sdot, 32);
    if (lane == 0) out[wave] = sdot * (1.f / 32.f);
}

// ---------------- launch ----------------

extern "C" void kernel_launch(void* const* d_in, const int* in_sizes, int n_in,
                              void* d_out, int out_size, void* d_ws, size_t ws_size,
                              hipStream_t stream) {
    const float* uE      = (const float*)d_in[0];
    const float* iE      = (const float*)d_in[1];
    const float* L_val   = (const float*)d_in[2];
    const int*   L_row   = (const int*)d_in[3];
    const int*   L_col   = (const int*)d_in[4];
    const int*   userIdx = (const int*)d_in[5];
    const int*   itemIdx = (const int*)d_in[6];

    const int userNum = in_sizes[0] / EMBED;   // 100000
    const int itemNum = in_sizes[1] / EMBED;   // 50000
    const int N = userNum + itemNum;           // 150000
    const int E = in_sizes[2];                 // 2000000
    const int B = in_sizes[5];                 // 16384
    float* out = (float*)d_out;

    char* ws = (char*)d_ws;
    size_t off = 0;
    auto alloc = [&](size_t bytes) -> void* {
        void* p = ws + off;
        off += (bytes + 1023) & ~(size_t)1023;
        return p;
    };
    const int NBUCKETS = (N + (1 << NB_SH) - 1) >> NB_SH;   // 147
    unsigned* h0 = (unsigned*)alloc((size_t)N * EMBED);   // int8
    unsigned* h1 = (unsigned*)alloc((size_t)N * EMBED);   // int8
    unsigned* h2 = (unsigned*)alloc((size_t)N * EMBED);   // int8
    float* sc0   = (float*)alloc((size_t)N * 4);
    float* sc1   = (float*)alloc((size_t)N * 4);
    float* sc2   = (float*)alloc((size_t)N * 4);
    int2*  edges = (int2*) alloc((size_t)E * 8 + 256);    // +slack
    long long* bedges = (long long*)alloc((size_t)NBUCKETS * BCAP * 8);
    int*   rs    = (int*)  alloc((size_t)(N + 1) * 4);
    int*   bcnt  = (int*)  alloc(1024);
    (void)off; (void)ws_size; (void)n_in; (void)out_size;

    // zero bcnt
    (void)hipMemsetAsync(bcnt, 0, 1024, stream);

    // CSR build: passA (+fused cvt) -> passB
    const int CA  = (E + T_TILE - 1) / T_TILE;     // 489
    const int CVB = (N + 7) / 8;                   // 18750
    passA_cvt<<<CA + CVB, 256, 0, stream>>>(L_row, L_col, L_val, bcnt, bedges, E,
                                            uE, iE, h0, sc0, userNum, N, CA);
    passB<<<NBUCKETS, 1024, 0, stream>>>(bedges, bcnt, rs, edges, N, E, NBUCKETS);

    // propagation: 8 rows per 256-thread block (2 rows/wave)
    const int spmm_blocks = (N + 7) / 8;
    spmm_kernel<<<spmm_blocks, 256, 0, stream>>>(rs, edges, h0, sc0, h1, sc1, N);
    spmm_kernel<<<spmm_blocks, 256, 0, stream>>>(rs, edges, h1, sc1, h2, sc2, N);

    // fused layer-3-restricted spmm + layer-sum + dot
    spmm_pair<<<(B + 3) / 4, 256, 0, stream>>>(rs, edges, h1, sc1, h2, sc2, uE, iE,
                                               userIdx, itemIdx, out, B, userNum);
}

// Round 14
// 294.498 us; speedup vs baseline: 2.7449x; 1.0774x over previous
//
#include <hip/hip_runtime.h>
#include <hip/hip_fp16.h>

#define EMBED 128
#define CHUNK 8             // gathers per inner batch
#define T_TILE 4096
#define NB_SH 10            // 1024 rows per bucket
#define BCAP 32768          // fixed per-bucket capacity (avg ~13.6K)

// int8 storage: per-row symmetric quant (R4/R7-proven, absmax 4.96e-5).
// q = rint(h*127/amax)+128 in [1,255]; h = (q-128)*s, s = amax/127.
// SpMM: acc = sum q*(v*s_col), cb = sum (v*s_col); h_out = acc - 128*cb.
//
// CSR build = bucket sort (LDS-staged contiguous writes; avoids R11's 8x write
// amplification). R13 lesson: fusing cvt into passA starved cvt at 27% occupancy
// (53 KB LDS reserved per-kernel). cvt now rides in passB's grid instead: passB
// is 147 one-per-CU blocks (~57% of CUs idle), ~9 KB LDS -> cvt blocks run at
// full occupancy on the idle CUs, concurrently, in the same dispatch.

// ---------------- CSR build: passA (bucket sort, standalone, R2-proven) --------------

__global__ __launch_bounds__(256) void passA(const int* __restrict__ row,
                                             const int* __restrict__ col,
                                             const float* __restrict__ val,
                                             int* __restrict__ bcnt,
                                             long long* __restrict__ bedges, int E) {
    __shared__ int sh_scan[256];
    __shared__ int sh_start[256];
    __shared__ int sh_cur[256];
    __shared__ int sh_base[256];   // global (fixed-region) base per bucket
    __shared__ long long sh_data[T_TILE];
    __shared__ int sh_gpos[T_TILE];
    const int t0  = blockIdx.x * T_TILE;
    const int tid = threadIdx.x;

    sh_scan[tid] = 0;
    __syncthreads();
    #pragma unroll
    for (int i = 0; i < T_TILE / 256; ++i) {
        int idx = t0 + i * 256 + tid;
        if (idx < E) atomicAdd(&sh_scan[row[idx] >> NB_SH], 1);
    }
    __syncthreads();
    int x = sh_scan[tid];
    __syncthreads();
    for (int off = 1; off < 256; off <<= 1) {
        int t = (tid >= off) ? sh_scan[tid - off] : 0;
        __syncthreads();
        sh_scan[tid] += t;
        __syncthreads();
    }
    int excl = sh_scan[tid] - x;
    sh_start[tid] = excl;
    sh_cur[tid]   = excl;
    sh_base[tid]  = (x > 0) ? (tid * BCAP + atomicAdd(&bcnt[tid], x)) : 0;
    __syncthreads();
    #pragma unroll
    for (int i = 0; i < T_TILE / 256; ++i) {
        int idx = t0 + i * 256 + tid;
        if (idx < E) {
            int   r = row[idx];
            int   c = col[idx];
            float v = val[idx];
            int   b = r >> NB_SH;
            int   p = atomicAdd(&sh_cur[b], 1);
            unsigned lo = (unsigned)(((r & ((1 << NB_SH) - 1)) << 18) | c);
            sh_data[p] = ((long long)__float_as_int(v) << 32) | (long long)lo;
            sh_gpos[p] = sh_base[b] + (p - sh_start[b]);
        }
    }
    __syncthreads();
    int tot = sh_scan[255];
    for (int p = tid; p < tot; p += 256) {
        bedges[sh_gpos[p]] = sh_data[p];
    }
}

// ---------------- passB (+ concurrent fp32->int8 cvt on the idle CUs) ----------------

__global__ __launch_bounds__(1024) void passB_cvt(const long long* __restrict__ bedges,
                                                  const int* __restrict__ bcnt,
                                                  int* __restrict__ rs,
                                                  int2* __restrict__ edges,
                                                  int N, int E, int nbuckets,
                                                  const float* __restrict__ uE,
                                                  const float* __restrict__ iE,
                                                  unsigned* __restrict__ h0,
                                                  float* __restrict__ sc0,
                                                  int userNum) {
    __shared__ int sh_hist[1024];   // row hist, then reused as cursor
    __shared__ int sh_scan[1024];
    __shared__ int sh_bc[256];
    __shared__ int sh_gbase;
    const int tid = threadIdx.x;

    if ((int)blockIdx.x >= nbuckets) {
        // ---- cvt branch: feats -> int8 per-row (2 rows/wave, 32 lanes each) ----
        int vb   = (int)blockIdx.x - nbuckets;
        int gid  = vb * 1024 + tid;
        int wave = gid >> 6;
        int lane = tid & 63;
        int half = lane >> 5;
        int l32  = lane & 31;
        int r    = wave * 2 + half;
        if (r >= N) return;
        const float* src = (r < userNum) ? (uE + (size_t)r * EMBED)
                                         : (iE + (size_t)(r - userNum) * EMBED);
        float4 a = *(const float4*)(src + 4 * l32);
        float am = fmaxf(fmaxf(fabsf(a.x), fabsf(a.y)), fmaxf(fabsf(a.z), fabsf(a.w)));
        #pragma unroll
        for (int off = 16; off > 0; off >>= 1)
            am = fmaxf(am, __shfl_xor(am, off));
        float s   = am * (1.f / 127.f);
        float inv = (am > 0.f) ? (127.f / am) : 0.f;
        int q0 = (int)rintf(a.x * inv) + 128;
        int q1 = (int)rintf(a.y * inv) + 128;
        int q2 = (int)rintf(a.z * inv) + 128;
        int q3 = (int)rintf(a.w * inv) + 128;
        unsigned w = (unsigned)q0 | ((unsigned)q1 << 8) | ((unsigned)q2 << 16)
                   | ((unsigned)q3 << 24);
        h0[(size_t)r * 32 + l32] = w;
        if (l32 == 0) sc0[r] = s;
        return;
    }

    // ---- passB branch (R2-proven body) ----
    const int b    = blockIdx.x;
    const int base = b << NB_SH;
    const int cnt  = bcnt[b];
    const long long* seg = bedges + (size_t)b * BCAP;

    sh_hist[tid] = 0;
    if (tid < nbuckets) sh_bc[tid] = bcnt[tid];
    __syncthreads();
    if (tid == 0) {
        int g = 0;
        for (int j = 0; j < b; ++j) g += sh_bc[j];
        sh_gbase = g;
    }
    for (int k = tid; k < cnt; k += 1024) {
        unsigned lo = (unsigned)seg[k];
        atomicAdd(&sh_hist[lo >> 18], 1);
    }
    __syncthreads();
    int x = sh_hist[tid];
    sh_scan[tid] = x;
    __syncthreads();
    for (int off = 1; off < 1024; off <<= 1) {
        int t = (tid >= off) ? sh_scan[tid - off] : 0;
        __syncthreads();
        sh_scan[tid] += t;
        __syncthreads();
    }
    int excl = sh_scan[tid] - x;
    int gbase = sh_gbase;
    int rrow = base + tid;
    if (rrow < N) rs[rrow] = gbase + excl;
    if (b == nbuckets - 1 && tid == 0) rs[N] = E;
    sh_hist[tid] = excl;
    __syncthreads();
    for (int k = tid; k < cnt; k += 1024) {
        long long be = seg[k];
        unsigned lo = (unsigned)be;
        int p = atomicAdd(&sh_hist[lo >> 18], 1);
        edges[gbase + p] = make_int2((int)(lo & 0x3FFFF), (int)(be >> 32));
    }
}

// ---------------- gather loop: lane-held edges + shfl distribution, int8 h -----------

#define GATHER_LOOP_I8(HSRC, SCSRC)                                           \
    for (int t = s; t < e; t += 32) {                                         \
        int ecl = t + l32;                                                    \
        ecl = (ecl < e) ? ecl : (e - 1);                                      \
        int2 myed = edges[ecl];                                               \
        float mvs = __int_as_float(myed.y) * SCSRC[myed.x];                   \
        int nb = e - t;                                                       \
        nb = (nb < 32) ? nb : 32;                                             \
        for (int k = 0; k < nb; k += CHUNK) {                                 \
            unsigned raw[CHUNK];                                              \
            float tv[CHUNK];                                                  \
            _Pragma("unroll")                                                 \
            for (int j = 0; j < CHUNK; ++j) {                                 \
                int   c  = __shfl(myed.x, k + j, 32);                         \
                float tj = __shfl(mvs, k + j, 32);                            \
                bool ok  = (k + j) < nb;                                      \
                tv[j]    = ok ? tj : 0.f;                                     \
                raw[j]   = HSRC[(size_t)c * 32 + l32];                        \
            }                                                                 \
            _Pragma("unroll")                                                 \
            for (int j = 0; j < CHUNK; ++j) {                                 \
                unsigned r = raw[j];                                          \
                float tj = tv[j];                                             \
                cb += tj;                                                     \
                acc.x = fmaf((float)(unsigned char)(r),       tj, acc.x);     \
                acc.y = fmaf((float)(unsigned char)(r >> 8),  tj, acc.y);     \
                acc.z = fmaf((float)(unsigned char)(r >> 16), tj, acc.z);     \
                acc.w = fmaf((float)(unsigned char)(r >> 24), tj, acc.w);     \
            }                                                                 \
        }                                                                     \
    }

// ---------------- SpMM: 2 rows/wave (32 lanes each), int8 h, fp32 acc ----------------
// R7-proven: 54.6 us/dispatch, VALUBusy 78%.

__global__ void spmm_kernel(const int* __restrict__ rs, const int2* __restrict__ edges,
                            const unsigned* __restrict__ hin,
                            const float* __restrict__ scin,
                            unsigned* __restrict__ hout, float* __restrict__ scout,
                            int N) {
    int gid  = blockIdx.x * blockDim.x + threadIdx.x;
    int wave = gid >> 6;
    int lane = threadIdx.x & 63;
    int half = lane >> 5;
    int l32  = lane & 31;
    int row  = wave * 2 + half;
    if (row >= N) return;
    int s = rs[row], e = rs[row + 1];
    float4 acc = make_float4(0.f, 0.f, 0.f, 0.f);
    float cb = 0.f;

    GATHER_LOOP_I8(hin, scin)

    float b = 128.f * cb;
    acc.x -= b; acc.y -= b; acc.z -= b; acc.w -= b;
    float am = fmaxf(fmaxf(fabsf(acc.x), fabsf(acc.y)), fmaxf(fabsf(acc.z), fabsf(acc.w)));
    #pragma unroll
    for (int off = 16; off > 0; off >>= 1)
        am = fmaxf(am, __shfl_xor(am, off));
    float sq  = am * (1.f / 127.f);
    float inv = (am > 0.f) ? (127.f / am) : 0.f;
    int q0 = (int)rintf(acc.x * inv) + 128;
    int q1 = (int)rintf(acc.y * inv) + 128;
    int q2 = (int)rintf(acc.z * inv) + 128;
    int q3 = (int)rintf(acc.w * inv) + 128;
    unsigned w = (unsigned)q0 | ((unsigned)q1 << 8) | ((unsigned)q2 << 16)
               | ((unsigned)q3 << 24);
    hout[(size_t)row * 32 + l32] = w;
    if (l32 == 0) scout[row] = sq;
}

// ---------------- fused tail: per pair b, half0 = u-row, half1 = v-row ----------------

__global__ void spmm_pair(const int* __restrict__ rs, const int2* __restrict__ edges,
                          const unsigned* __restrict__ h1, const float* __restrict__ sc1,
                          const unsigned* __restrict__ h2, const float* __restrict__ sc2,
                          const float* __restrict__ uE, const float* __restrict__ iE,
                          const int* __restrict__ uIdx, const int* __restrict__ vIdx,
                          float* __restrict__ out, int B, int userNum) {
    int gid  = blockIdx.x * blockDim.x + threadIdx.x;
    int wave = gid >> 6;
    int lane = threadIdx.x & 63;
    int half = lane >> 5;
    int l32  = lane & 31;
    if (wave >= B) return;
    int row;
    const float* emb;
    if (half == 0) {
        int u = uIdx[wave];
        row = u;
        emb = uE + (size_t)u * EMBED;
    } else {
        int it = vIdx[wave];
        row = userNum + it;
        emb = iE + (size_t)it * EMBED;
    }
    float4 acc = *(const float4*)(emb + 4 * l32);   // feats, exact fp32
    {
        unsigned r1 = h1[(size_t)row * 32 + l32];
        unsigned r2 = h2[(size_t)row * 32 + l32];
        float s1 = sc1[row];
        float s2 = sc2[row];
        acc.x += ((float)(unsigned char)(r1)       - 128.f) * s1
               + ((float)(unsigned char)(r2)       - 128.f) * s2;
        acc.y += ((float)(unsigned char)(r1 >> 8)  - 128.f) * s1
               + ((float)(unsigned char)(r2 >> 8)  - 128.f) * s2;
        acc.z += ((float)(unsigned char)(r1 >> 16) - 128.f) * s1
               + ((float)(unsigned char)(r2 >> 16) - 128.f) * s2;
        acc.w += ((float)(unsigned char)(r1 >> 24) - 128.f) * s1
               + ((float)(unsigned char)(r2 >> 24) - 128.f) * s2;
    }
    float cb = 0.f;
    int s = rs[row], e = rs[row + 1];

    GATHER_LOOP_I8(h2, sc2)

    float b = 128.f * cb;
    acc.x -= b; acc.y -= b; acc.z -= b; acc.w -= b;

    float ox = __shfl_xor(acc.x, 32);
    float oy = __shfl_xor(acc.y, 32);
    float oz = __shfl_xor(acc.z, 32);
    float ow = __shfl_xor(acc.w, 32);
    float sdot = acc.x * ox + acc.y * oy + acc.z * oz + acc.w * ow;
    #pragma unroll
    for (int off = 16; off > 0; off >>= 1) sdot += __shfl_down(sdot, off, 32);
    sdot += __shfl_down(sdot, 32);
    if (lane == 0) out[wave] = sdot * (1.f / 32.f);
}

// ---------------- launch ----------------

extern "C" void kernel_launch(void* const* d_in, const int* in_sizes, int n_in,
                              void* d_out, int out_size, void* d_ws, size_t ws_size,
                              hipStream_t stream) {
    const float* uE      = (const float*)d_in[0];
    const float* iE      = (const float*)d_in[1];
    const float* L_val   = (const float*)d_in[2];
    const int*   L_row   = (const int*)d_in[3];
    const int*   L_col   = (const int*)d_in[4];
    const int*   userIdx = (const int*)d_in[5];
    const int*   itemIdx = (const int*)d_in[6];

    const int userNum = in_sizes[0] / EMBED;   // 100000
    const int itemNum = in_sizes[1] / EMBED;   // 50000
    const int N = userNum + itemNum;           // 150000
    const int E = in_sizes[2];                 // 2000000
    const int B = in_sizes[5];                 // 16384
    float* out = (float*)d_out;

    char* ws = (char*)d_ws;
    size_t off = 0;
    auto alloc = [&](size_t bytes) -> void* {
        void* p = ws + off;
        off += (bytes + 1023) & ~(size_t)1023;
        return p;
    };
    const int NBUCKETS = (N + (1 << NB_SH) - 1) >> NB_SH;   // 147
    unsigned* h0 = (unsigned*)alloc((size_t)N * EMBED);   // int8
    unsigned* h1 = (unsigned*)alloc((size_t)N * EMBED);   // int8
    unsigned* h2 = (unsigned*)alloc((size_t)N * EMBED);   // int8
    float* sc0   = (float*)alloc((size_t)N * 4);
    float* sc1   = (float*)alloc((size_t)N * 4);
    float* sc2   = (float*)alloc((size_t)N * 4);
    int2*  edges = (int2*) alloc((size_t)E * 8 + 256);    // +slack
    long long* bedges = (long long*)alloc((size_t)NBUCKETS * BCAP * 8);
    int*   rs    = (int*)  alloc((size_t)(N + 1) * 4);
    int*   bcnt  = (int*)  alloc(1024);
    (void)off; (void)ws_size; (void)n_in; (void)out_size;

    // zero bcnt
    (void)hipMemsetAsync(bcnt, 0, 1024, stream);

    // CSR build: passA -> passB (+concurrent cvt on idle CUs)
    const int CA  = (E + T_TILE - 1) / T_TILE;     // 489
    const int CVB = (N + 31) / 32;                 // 4688 cvt blocks @1024 thr
    passA<<<CA, 256, 0, stream>>>(L_row, L_col, L_val, bcnt, bedges, E);
    passB_cvt<<<NBUCKETS + CVB, 1024, 0, stream>>>(bedges, bcnt, rs, edges,
                                                   N, E, NBUCKETS,
                                                   uE, iE, h0, sc0, userNum);

    // propagation: 8 rows per 256-thread block (2 rows/wave)
    const int spmm_blocks = (N + 7) / 8;
    spmm_kernel<<<spmm_blocks, 256, 0, stream>>>(rs, edges, h0, sc0, h1, sc1, N);
    spmm_kernel<<<spmm_blocks, 256, 0, stream>>>(rs, edges, h1, sc1, h2, sc2, N);

    // fused layer-3-restricted spmm + layer-sum + dot
    spmm_pair<<<(B + 3) / 4, 256, 0, stream>>>(rs, edges, h1, sc1, h2, sc2, uE, iE,
                                               userIdx, itemIdx, out, B, userNum);
}